// Round 21
// baseline (121.940 us; speedup 1.0000x reference)
//
#include <hip/hip_runtime.h>

#define N_VEC   131072
#define D       64
#define KCODES  1024
#define NT      64            // code tiles of 16
#define BLK     256
#define VPB     64            // vectors per block (16 per wave: 1 b-tile)
#define CH      2             // code tiles staged per LDS chunk
#define NCH     (NT / CH)     // 32 chunks

typedef __attribute__((ext_vector_type(8))) short bf16x8;
typedef __attribute__((ext_vector_type(4))) float f32x4;

// direct global->LDS 16B DMA (no VGPR round trip; LDS dest linear in lane id)
#define GLD16(dst, src) __builtin_amdgcn_global_load_lds(                      \
    (const __attribute__((address_space(1))) void*)(src),                      \
    (__attribute__((address_space(3))) void*)(dst), 16, 0, 0)

// ws layout:
// [0,4096)          int counts[1024]
// [4096,4100)       float sse
// [5120,9216)       float esq[1024]
// [16384,81920)     float4 efrag[64*64]      (esq in C-row fragment order)
// [81920,344064)    bf16x8 afrag[64*4*64]    (codebook hi/lo MFMA A-fragments)

__device__ __forceinline__ float4 f4fma(float4 a, float4 b, float4 c) {
    return make_float4(fmaf(a.x, b.x, c.x), fmaf(a.y, b.y, c.y),
                       fmaf(a.z, b.z, c.z), fmaf(a.w, b.w, c.w));
}
__device__ __forceinline__ float f4rsum(float4 a) {
    return (a.x + a.y) + (a.z + a.w);
}
__device__ __forceinline__ unsigned short f2bf(float f) {
    union { float f; unsigned u; } x; x.f = f;
    unsigned r = x.u + 0x7FFFu + ((x.u >> 16) & 1u);
    return (unsigned short)(r >> 16);
}
__device__ __forceinline__ float bf2f(unsigned short h) {
    union { unsigned u; float f; } x; x.u = ((unsigned)h) << 16;
    return x.f;
}
__device__ __forceinline__ int   f_as_i(float f) { union { float f; int i; } x; x.f = f; return x.i; }
__device__ __forceinline__ float i_as_f(int i)   { union { int i; float f; } x; x.i = i; return x.f; }

// esq + codebook MFMA A-fragments (hi/lo bf16 planes) + esq fragment table (R8 format).
__global__ void prep_kernel(const float* __restrict__ cb, float* __restrict__ esq,
                            bf16x8* __restrict__ afrag, float4* __restrict__ efrag) {
    __shared__ float sesq[64];
    const int tid = threadIdx.x;
    const int c0  = blockIdx.x * 64;
    if (tid < 64) {
        const float4* c4 = reinterpret_cast<const float4*>(cb + (size_t)(c0 + tid) * D);
        float4 p = make_float4(0.f, 0.f, 0.f, 0.f);
        #pragma unroll
        for (int i = 0; i < 16; ++i) { float4 v = c4[i]; p = f4fma(v, v, p); }
        float e = f4rsum(p);
        esq[c0 + tid] = e;
        sesq[tid] = e;
    }
    __syncthreads();
    const int tt = tid >> 6;             // local tile 0..3
    const int L  = tid & 63;
    const int t  = blockIdx.x * 4 + tt;  // global tile
    const int g  = L >> 4;
    const int r  = t * 16 + (L & 15);
    #pragma unroll
    for (int ks = 0; ks < 2; ++ks) {
        const float* src = cb + (size_t)r * D + ks * 32 + g * 8;
        bf16x8 h, l;
        #pragma unroll
        for (int e = 0; e < 8; ++e) {
            float f = src[e];
            unsigned short hb = f2bf(f);
            float lo = f - bf2f(hb);
            h[e] = (short)hb;
            l[e] = (short)f2bf(lo);
        }
        afrag[(t * 4 + ks * 2 + 0) * 64 + L] = h;
        afrag[(t * 4 + ks * 2 + 1) * 64 + L] = l;
    }
    // raw esq in C/D fragment layout (lane reg j <-> code row g*4+j)
    float4 ef;
    ef.x = sesq[tt * 16 + g * 4 + 0];
    ef.y = sesq[tt * 16 + g * 4 + 1];
    ef.z = sesq[tt * 16 + g * 4 + 2];
    ef.w = sesq[tt * 16 + g * 4 + 3];
    efrag[t * 64 + L] = ef;
}

// descending (value, idx) lexicographic insert into sorted-3 list
__device__ __forceinline__ void insd(float ov, int og,
                                     float& v0, float& v1, float& v2,
                                     int& g0, int& g1, int& g2) {
    bool b1 = (ov > v0) || (ov == v0 && og < g0);
    bool b2 = (ov > v1) || (ov == v1 && og < g1);
    bool b3 = (ov > v2) || (ov == v2 && og < g2);
    float nv2 = b2 ? v1 : (b3 ? ov : v2);
    int   ng2 = b2 ? g1 : (b3 ? og : g2);
    float nv1 = b1 ? v0 : (b2 ? ov : v1);
    int   ng1 = b1 ? g0 : (b2 ? og : g1);
    v0 = b1 ? ov : v0;
    g0 = b1 ? og : g0;
    v1 = nv1; g1 = ng1; v2 = nv2; g2 = ng2;
}

__launch_bounds__(BLK)
__global__ void vq_fused(const float* __restrict__ z_e, const float* __restrict__ cb,
                         const float* __restrict__ esq,
                         const float4* __restrict__ afrag4, const float4* __restrict__ efrag,
                         float* __restrict__ zq_out, float* __restrict__ idx_out,
                         float* __restrict__ sse, int* __restrict__ counts) {
    __shared__ float4 scb[2][CH * 4 * 64];   // 2 x 8 KB (double-buffered A-frags)
    __shared__ float4 sef[2][CH * 64];       // 2 x 2 KB (esq frags)
    // epilogue overlays on scb[0] (dead after main loop + barrier); disjoint ranges:
    // scand [0,768) | sZsq [1024,1280) | sS0 [1280,1536) | sS1v [1536,1792)
    // sS2v [1792,2048) | sred [2048,2064)   -- all within scb[0]'s 8 KB
    char* ovl = (char*)&scb[0][0];
    int  (*scand)[3] = reinterpret_cast<int(*)[3]>(ovl);
    float* sZsq = reinterpret_cast<float*>(ovl + 1024);
    float* sS0  = reinterpret_cast<float*>(ovl + 1280);
    float* sS1v = reinterpret_cast<float*>(ovl + 1536);
    float* sS2v = reinterpret_cast<float*>(ovl + 1792);
    float* sred = reinterpret_cast<float*>(ovl + 2048);

    const int tid  = threadIdx.x;
    const int wave = tid >> 6;
    const int L    = tid & 63;
    const int lrow = L & 15;
    const int g    = L >> 4;
    const size_t vbase = (size_t)blockIdx.x * VPB + wave * 16;

    // ---- B-fragments: 1 vector-tile of 16, hi/lo bf16 split, k = g*8+e ----
    bf16x8 zhi[2], zlo[2];
    #pragma unroll
    for (int ks = 0; ks < 2; ++ks) {
        const float* zp = z_e + (vbase + lrow) * D + ks * 32 + g * 8;
        float4 u0 = *reinterpret_cast<const float4*>(zp);
        float4 u1 = *reinterpret_cast<const float4*>(zp + 4);
        float fv[8] = {u0.x, u0.y, u0.z, u0.w, u1.x, u1.y, u1.z, u1.w};
        bf16x8 h, l;
        #pragma unroll
        for (int e = 0; e < 8; ++e) {
            unsigned short hb = f2bf(fv[e]);
            float lo = fv[e] - bf2f(hb);
            h[e] = (short)hb;
            l[e] = (short)f2bf(lo);
        }
        zhi[ks] = h; zlo[ks] = l;
    }

    // packed top-3 stream state (s-domain: larger = nearer code)
    float m1 = -INFINITY, m2 = -INFINITY, m3 = -INFINITY;

    // prologue: stage chunk 0 into buffer 0
    #pragma unroll
    for (int i = 0; i < 2; ++i) GLD16(&scb[0][i * BLK + tid], afrag4 + i * BLK + tid);
    if (tid < CH * 64) GLD16(&sef[0][tid], efrag + tid);

    int cur = 0;
    for (int c = 0; c < NCH; ++c) {
        __syncthreads();   // drains vmcnt -> buf[cur] ready; prev compute done
        if (c + 1 < NCH) {
            const float4* gA = afrag4 + (size_t)(c + 1) * (CH * 4 * 64);
            const float4* gE = efrag + (size_t)(c + 1) * (CH * 64);
            #pragma unroll
            for (int i = 0; i < 2; ++i) GLD16(&scb[cur ^ 1][i * BLK + tid], gA + i * BLK + tid);
            if (tid < CH * 64) GLD16(&sef[cur ^ 1][tid], gE + tid);
        }

        #pragma unroll
        for (int tt = 0; tt < CH; ++tt) {
            const int t = c * CH + tt;
            const bf16x8* fr = reinterpret_cast<const bf16x8*>(&scb[cur][tt * 256]);
            bf16x8 Ah0 = fr[0 * 64 + L];
            bf16x8 Al0 = fr[1 * 64 + L];
            bf16x8 Ah1 = fr[2 * 64 + L];
            bf16x8 Al1 = fr[3 * 64 + L];
            float4 ef  = sef[cur][tt * 64 + L];

            // R8 verbatim: two independent chains (hi*hi depth 2, cross depth 4)
            f32x4 aA = (f32x4){0.f, 0.f, 0.f, 0.f};
            f32x4 aB = (f32x4){0.f, 0.f, 0.f, 0.f};
            aA = __builtin_amdgcn_mfma_f32_16x16x32_bf16(Ah0, zhi[0], aA, 0, 0, 0);
            aB = __builtin_amdgcn_mfma_f32_16x16x32_bf16(Ah0, zlo[0], aB, 0, 0, 0);
            aB = __builtin_amdgcn_mfma_f32_16x16x32_bf16(Al0, zhi[0], aB, 0, 0, 0);
            aA = __builtin_amdgcn_mfma_f32_16x16x32_bf16(Ah1, zhi[1], aA, 0, 0, 0);
            aB = __builtin_amdgcn_mfma_f32_16x16x32_bf16(Ah1, zlo[1], aB, 0, 0, 0);
            aB = __builtin_amdgcn_mfma_f32_16x16x32_bf16(Al1, zhi[1], aB, 0, 0, 0);

            #pragma unroll
            for (int j = 0; j < 4; ++j) {
                float ej = (j == 0) ? ef.x : (j == 1) ? ef.y : (j == 2) ? ef.z : ef.w;
                // s = 2*dot - esq  (rank only; exact rescore later)
                float s = fmaf(2.0f, aA[j], fmaf(2.0f, aB[j], -ej));
                // pack 8-bit local code id (complement: fmax prefers lower code)
                int komp = 255 - ((t << 2) | j);   // wave-uniform
                float pd = i_as_f((f_as_i(s) & 0xFFFFFF00) | komp);
                float t1 = fminf(m1, pd); m1 = fmaxf(m1, pd);
                float t2 = fminf(m2, t1); m2 = fmaxf(m2, t1);
                m3 = fmaxf(m3, t2);
            }
        }
        cur ^= 1;
    }

    __syncthreads();   // all waves done with scb -> overlays safe

    // ---- decode + cross-lane (4 g-groups) merge with global-idx tie-break ----
    {
        float v0, v1, v2; int g0, g1, g2;
        {
            int p0 = f_as_i(m1), p1 = f_as_i(m2), p2 = f_as_i(m3);
            int c0 = 255 - (p0 & 255), c1 = 255 - (p1 & 255), c2 = 255 - (p2 & 255);
            v0 = i_as_f(p0 & ~255); g0 = (c0 >> 2) * 16 + g * 4 + (c0 & 3);
            v1 = i_as_f(p1 & ~255); g1 = (c1 >> 2) * 16 + g * 4 + (c1 & 3);
            v2 = i_as_f(p2 & ~255); g2 = (c2 >> 2) * 16 + g * 4 + (c2 & 3);
        }
        #pragma unroll
        for (int m = 16; m <= 32; m <<= 1) {
            float ov0 = __shfl_xor(v0, m), ov1 = __shfl_xor(v1, m), ov2 = __shfl_xor(v2, m);
            int   og0 = __shfl_xor(g0, m), og1 = __shfl_xor(g1, m), og2 = __shfl_xor(g2, m);
            insd(ov0, og0, v0, v1, v2, g0, g1, g2);
            insd(ov1, og1, v0, v1, v2, g0, g1, g2);
            insd(ov2, og2, v0, v1, v2, g0, g1, g2);
        }
        if (g == 0) {
            int lv = wave * 16 + lrow;
            scand[lv][0] = g0; scand[lv][1] = g1; scand[lv][2] = g2;
        }
    }
    __syncthreads();

    // ---- fused exact rescore (bit-replicates reference), 4 threads/vector ----
    // 256 tasks: sub0 = zsq, sub1 = dot(cand0), sub2 = dot(cand1), sub3 = dot(cand2)
    const int vid = tid & (VPB - 1);
    const int sub = tid >> 6;
    const size_t n = (size_t)blockIdx.x * VPB + vid;
    {
        const float4* z4 = reinterpret_cast<const float4*>(z_e + n * D);
        if (sub == 0) {
            float4 pq = make_float4(0.f, 0.f, 0.f, 0.f);
            #pragma unroll
            for (int i = 0; i < 16; ++i) {
                float4 zz = z4[i];
                pq = f4fma(zz, zz, pq);
            }
            sZsq[vid] = f4rsum(pq);
        } else {
            int ci = scand[vid][sub - 1];
            const float4* cp = reinterpret_cast<const float4*>(cb + (size_t)ci * D);
            float4 s = make_float4(0.f, 0.f, 0.f, 0.f);
            #pragma unroll
            for (int i = 0; i < 16; ++i) {
                float4 zz = z4[i];
                s = f4fma(zz, cp[i], s);
            }
            float r = f4rsum(s);
            if (sub == 1) sS0[vid] = r;
            else if (sub == 2) sS1v[vid] = r;
            else sS2v[vid] = r;
        }
    }
    __syncthreads();

    float v = 0.f;
    if (sub == 0) {
        int ci0 = scand[vid][0], ci1 = scand[vid][1], ci2 = scand[vid][2];
        float zsq = sZsq[vid];
        float d0 = fmaf(-2.0f, sS0[vid], zsq + esq[ci0]);
        float d1 = fmaf(-2.0f, sS1v[vid], zsq + esq[ci1]);
        float d2 = fmaf(-2.0f, sS2v[vid], zsq + esq[ci2]);
        float bd = d0; int bi = ci0;
        if (d1 < bd || (d1 == bd && ci1 < bi)) { bd = d1; bi = ci1; }
        if (d2 < bd || (d2 == bd && ci2 < bi)) { bd = d2; bi = ci2; }
        idx_out[n] = (float)bi;
        atomicAdd(&counts[bi], 1);
        scand[vid][0] = bi;            // winner (scand slot reused)
        v = bd;
    }
    #pragma unroll
    for (int off = 32; off > 0; off >>= 1) v += __shfl_down(v, off);
    if ((tid & 63) == 0) sred[tid >> 6] = v;
    __syncthreads();   // winners + sred ready
    if (tid == 0) atomicAdd(sse, (sred[0] + sred[1]) + (sred[2] + sred[3]));

    // ---- coalesced z_q write: 64 vectors * 16 float4 ----
    const float4* cb4 = reinterpret_cast<const float4*>(cb);
    float4* zq4 = reinterpret_cast<float4*>(zq_out) + (size_t)blockIdx.x * (VPB * 16);
    #pragma unroll
    for (int i = 0; i < 4; ++i) {
        int mi  = i * BLK + tid;      // 0..1023
        int vec = mi >> 4;
        int e   = mi & 15;
        zq4[mi] = cb4[(size_t)scand[vec][0] * 16 + e];
    }
}

__global__ void finalize_kernel(const int* __restrict__ counts, const float* __restrict__ sse,
                                float* __restrict__ out_loss, float* __restrict__ out_perp) {
    __shared__ float red[256];
    int tid = threadIdx.x;
    float hsum = 0.f;
    for (int k = tid; k < KCODES; k += 256) {
        float p = (float)counts[k] / (float)N_VEC;
        hsum += p * logf(p + 1e-12f);
    }
    red[tid] = hsum;
    __syncthreads();
    for (int s = 128; s > 0; s >>= 1) {
        if (tid < s) red[tid] += red[tid + s];
        __syncthreads();
    }
    if (tid == 0) {
        out_loss[0] = 1.25f * sse[0] / 8388608.0f;   // (1+BETA) * mean
        out_perp[0] = expf(-red[0]);
    }
}

extern "C" void kernel_launch(void* const* d_in, const int* in_sizes, int n_in,
                              void* d_out, int out_size, void* d_ws, size_t ws_size,
                              hipStream_t stream) {
    const float* z_e = (const float*)d_in[0];
    const float* cb  = (const float*)d_in[1];

    float* out  = (float*)d_out;
    float* zq   = out;
    float* idxo = out + (size_t)N_VEC * D;          // 8388608
    float* loss = idxo + N_VEC;                     // +131072
    float* perp = loss + 1;

    char* ws = (char*)d_ws;
    int*    counts = (int*)ws;
    float*  sse    = (float*)(ws + 4096);
    float*  esq    = (float*)(ws + 5120);
    float4* efrag  = (float4*)(ws + 16384);
    bf16x8* afrag  = (bf16x8*)(ws + 81920);

    hipMemsetAsync(d_ws, 0, 5120, stream);          // zero counts + sse each call
    prep_kernel<<<16, 256, 0, stream>>>(cb, esq, afrag, efrag);
    vq_fused<<<N_VEC / VPB, BLK, 0, stream>>>(z_e, cb, esq, (const float4*)afrag, efrag,
                                              zq, idxo, sse, counts);
    finalize_kernel<<<1, 256, 0, stream>>>(counts, sse, loss, perp);
}

// Round 22
// 104.737 us; speedup vs baseline: 1.1643x; 1.1643x over previous
//
#include <hip/hip_runtime.h>

#define N_VEC   131072
#define D       64
#define KCODES  1024
#define NT      64            // code tiles of 16
#define BLK     256
#define VPB     128           // vectors per block (32 per wave: 2 b-tiles)
#define CH      4             // code tiles staged per LDS chunk
#define NCH     (NT / CH)     // 16 chunks

typedef __attribute__((ext_vector_type(8))) short bf16x8;
typedef __attribute__((ext_vector_type(4))) float f32x4;

// direct global->LDS 16B DMA (no VGPR round trip; LDS dest linear in lane id)
#define GLD16(dst, src) __builtin_amdgcn_global_load_lds(                      \
    (const __attribute__((address_space(1))) void*)(src),                      \
    (__attribute__((address_space(3))) void*)(dst), 16, 0, 0)

// ws layout:
// [0,4096)          int counts[1024]
// [4096,4100)       float sse
// [5120,9216)       float esq[1024]
// [16384,81920)     float4 efrag[64*64]      (einit = -esq/2 in C-row fragment order)
// [81920,344064)    bf16x8 afrag[64*4*64]    (codebook hi/lo MFMA A-fragments)

__device__ __forceinline__ float4 f4fma(float4 a, float4 b, float4 c) {
    return make_float4(fmaf(a.x, b.x, c.x), fmaf(a.y, b.y, c.y),
                       fmaf(a.z, b.z, c.z), fmaf(a.w, b.w, c.w));
}
__device__ __forceinline__ float f4rsum(float4 a) {
    return (a.x + a.y) + (a.z + a.w);
}
__device__ __forceinline__ unsigned short f2bf(float f) {
    union { float f; unsigned u; } x; x.f = f;
    unsigned r = x.u + 0x7FFFu + ((x.u >> 16) & 1u);
    return (unsigned short)(r >> 16);
}
__device__ __forceinline__ float bf2f(unsigned short h) {
    union { unsigned u; float f; } x; x.u = ((unsigned)h) << 16;
    return x.f;
}
__device__ __forceinline__ int   f_as_i(float f) { union { float f; int i; } x; x.f = f; return x.i; }
__device__ __forceinline__ float i_as_f(int i)   { union { int i; float f; } x; x.i = i; return x.f; }

// esq + codebook MFMA A-fragments (hi/lo bf16 planes) + einit fragment table.
__global__ void prep_kernel(const float* __restrict__ cb, float* __restrict__ esq,
                            bf16x8* __restrict__ afrag, float4* __restrict__ efrag) {
    __shared__ float sesq[64];
    const int tid = threadIdx.x;
    const int c0  = blockIdx.x * 64;
    if (tid < 64) {
        const float4* c4 = reinterpret_cast<const float4*>(cb + (size_t)(c0 + tid) * D);
        float4 p = make_float4(0.f, 0.f, 0.f, 0.f);
        #pragma unroll
        for (int i = 0; i < 16; ++i) { float4 v = c4[i]; p = f4fma(v, v, p); }
        float e = f4rsum(p);
        esq[c0 + tid] = e;
        sesq[tid] = e;
    }
    __syncthreads();
    const int tt = tid >> 6;             // local tile 0..3
    const int L  = tid & 63;
    const int t  = blockIdx.x * 4 + tt;  // global tile
    const int g  = L >> 4;
    const int r  = t * 16 + (L & 15);
    #pragma unroll
    for (int ks = 0; ks < 2; ++ks) {
        const float* src = cb + (size_t)r * D + ks * 32 + g * 8;
        bf16x8 h, l;
        #pragma unroll
        for (int e = 0; e < 8; ++e) {
            float f = src[e];
            unsigned short hb = f2bf(f);
            float lo = f - bf2f(hb);
            h[e] = (short)hb;
            l[e] = (short)f2bf(lo);
        }
        afrag[(t * 4 + ks * 2 + 0) * 64 + L] = h;
        afrag[(t * 4 + ks * 2 + 1) * 64 + L] = l;
    }
    // einit = -esq/2 in C/D fragment layout (lane reg j <-> code row g*4+j)
    float4 ef;
    ef.x = -0.5f * sesq[tt * 16 + g * 4 + 0];
    ef.y = -0.5f * sesq[tt * 16 + g * 4 + 1];
    ef.z = -0.5f * sesq[tt * 16 + g * 4 + 2];
    ef.w = -0.5f * sesq[tt * 16 + g * 4 + 3];
    efrag[t * 64 + L] = ef;
}

// descending (value, idx) lexicographic insert into sorted-3 list
__device__ __forceinline__ void insd(float ov, int og,
                                     float& v0, float& v1, float& v2,
                                     int& g0, int& g1, int& g2) {
    bool b1 = (ov > v0) || (ov == v0 && og < g0);
    bool b2 = (ov > v1) || (ov == v1 && og < g1);
    bool b3 = (ov > v2) || (ov == v2 && og < g2);
    float nv2 = b2 ? v1 : (b3 ? ov : v2);
    int   ng2 = b2 ? g1 : (b3 ? og : g2);
    float nv1 = b1 ? v0 : (b2 ? ov : v1);
    int   ng1 = b1 ? g0 : (b2 ? og : g1);
    v0 = b1 ? ov : v0;
    g0 = b1 ? og : g0;
    v1 = nv1; g1 = ng1; v2 = nv2; g2 = ng2;
}

__launch_bounds__(BLK)
__global__ void vq_fused(const float* __restrict__ z_e, const float* __restrict__ cb,
                         const float* __restrict__ esq,
                         const float4* __restrict__ afrag4, const float4* __restrict__ efrag,
                         float* __restrict__ zq_out, float* __restrict__ idx_out,
                         float* __restrict__ sse, int* __restrict__ counts) {
    __shared__ float4 scb[2][CH * 4 * 64];   // 2 x 16 KB (double-buffered A-frags)
    __shared__ float4 sef[2][CH * 64];       // 2 x 4 KB  (einit frags)
    // epilogue overlays on scb[0] (dead after main loop + barrier); disjoint ranges:
    // scand [0,1536) | sZsq [2048,2560) | sS1 [2560,3072) | sS2 [3072,3584)
    // sC2  [3584,4096) | sred [4096,4112)
    char* ovl = (char*)&scb[0][0];
    int  (*scand)[3] = reinterpret_cast<int(*)[3]>(ovl);
    float* sZsq = reinterpret_cast<float*>(ovl + 2048);
    float* sS1  = reinterpret_cast<float*>(ovl + 2560);
    float* sS2  = reinterpret_cast<float*>(ovl + 3072);
    float* sC2  = reinterpret_cast<float*>(ovl + 3584);
    float* sred = reinterpret_cast<float*>(ovl + 4096);

    const int tid  = threadIdx.x;
    const int wave = tid >> 6;
    const int L    = tid & 63;
    const int lrow = L & 15;
    const int g    = L >> 4;
    const size_t vbase = (size_t)blockIdx.x * VPB + wave * 32;

    // ---- B-fragments: 2 vector-tiles of 16, hi/lo bf16 split, k = g*8+e ----
    bf16x8 zhi[2][2], zlo[2][2];
    #pragma unroll
    for (int b = 0; b < 2; ++b) {
        #pragma unroll
        for (int ks = 0; ks < 2; ++ks) {
            const float* zp = z_e + (vbase + b * 16 + lrow) * D + ks * 32 + g * 8;
            float4 u0 = *reinterpret_cast<const float4*>(zp);
            float4 u1 = *reinterpret_cast<const float4*>(zp + 4);
            float fv[8] = {u0.x, u0.y, u0.z, u0.w, u1.x, u1.y, u1.z, u1.w};
            bf16x8 h, l;
            #pragma unroll
            for (int e = 0; e < 8; ++e) {
                unsigned short hb = f2bf(fv[e]);
                float lo = fv[e] - bf2f(hb);
                h[e] = (short)hb;
                l[e] = (short)f2bf(lo);
            }
            zhi[b][ks] = h; zlo[b][ks] = l;
        }
    }

    // packed top-3 stream state (r-domain: larger = nearer code)
    float m1[2], m2[2], m3[2];
    #pragma unroll
    for (int b = 0; b < 2; ++b) { m1[b] = m2[b] = m3[b] = -INFINITY; }

    // prologue: stage chunk 0 into buffer 0
    #pragma unroll
    for (int i = 0; i < 4; ++i) GLD16(&scb[0][i * BLK + tid], afrag4 + i * BLK + tid);
    GLD16(&sef[0][tid], efrag + tid);

    int cur = 0;
    for (int c = 0; c < NCH; ++c) {
        __syncthreads();   // drains vmcnt -> buf[cur] ready; prev compute done
        if (c + 1 < NCH) {
            const float4* gA = afrag4 + (size_t)(c + 1) * (CH * 4 * 64);
            const float4* gE = efrag + (size_t)(c + 1) * (CH * 64);
            #pragma unroll
            for (int i = 0; i < 4; ++i) GLD16(&scb[cur ^ 1][i * BLK + tid], gA + i * BLK + tid);
            GLD16(&sef[cur ^ 1][tid], gE + tid);
        }

        #pragma unroll
        for (int tt = 0; tt < CH; ++tt) {
            const int t = c * CH + tt;
            const bf16x8* fr = reinterpret_cast<const bf16x8*>(&scb[cur][tt * 256]);
            bf16x8 Ah0 = fr[0 * 64 + L];
            bf16x8 Al0 = fr[1 * 64 + L];
            bf16x8 Ah1 = fr[2 * 64 + L];
            bf16x8 Al1 = fr[3 * 64 + L];
            f32x4 einit;
            {
                float4 ef = sef[cur][tt * 64 + L];   // -esq/2
                einit[0] = ef.x; einit[1] = ef.y; einit[2] = ef.z; einit[3] = ef.w;
            }

            #pragma unroll
            for (int b = 0; b < 2; ++b) {
                // single 6-deep chain; C-init = -esq/2 -> acc = dot - esq/2
                f32x4 acc;
                acc = __builtin_amdgcn_mfma_f32_16x16x32_bf16(Ah0, zhi[b][0], einit, 0, 0, 0);
                acc = __builtin_amdgcn_mfma_f32_16x16x32_bf16(Ah0, zlo[b][0], acc, 0, 0, 0);
                acc = __builtin_amdgcn_mfma_f32_16x16x32_bf16(Al0, zhi[b][0], acc, 0, 0, 0);
                acc = __builtin_amdgcn_mfma_f32_16x16x32_bf16(Ah1, zhi[b][1], acc, 0, 0, 0);
                acc = __builtin_amdgcn_mfma_f32_16x16x32_bf16(Ah1, zlo[b][1], acc, 0, 0, 0);
                acc = __builtin_amdgcn_mfma_f32_16x16x32_bf16(Al1, zhi[b][1], acc, 0, 0, 0);

                #pragma unroll
                for (int j = 0; j < 4; ++j) {
                    // pack 8-bit local id (complement: fmax prefers lower code)
                    int komp = 255 - ((t << 2) | j);   // wave-uniform SGPR
                    float pd = i_as_f((f_as_i(acc[j]) & 0xFFFFFF00) | komp);  // v_and_or
                    // 4-op top-3 insert (min + med3 + 2 max)
                    float mn = fminf(m2[b], pd);
                    float md = __builtin_amdgcn_fmed3f(m1[b], pd, m2[b]);
                    m1[b] = fmaxf(m1[b], pd);
                    m2[b] = md;
                    m3[b] = fmaxf(m3[b], mn);
                }
            }
        }
        cur ^= 1;
    }

    __syncthreads();   // all waves done with scb -> overlays safe

    // ---- decode + cross-lane (4 g-groups) merge with global-idx tie-break ----
    #pragma unroll
    for (int b = 0; b < 2; ++b) {
        float v0, v1, v2; int g0, g1, g2;
        {
            int p0 = f_as_i(m1[b]), p1 = f_as_i(m2[b]), p2 = f_as_i(m3[b]);
            int c0 = 255 - (p0 & 255), c1 = 255 - (p1 & 255), c2 = 255 - (p2 & 255);
            v0 = i_as_f(p0 & ~255); g0 = (c0 >> 2) * 16 + g * 4 + (c0 & 3);
            v1 = i_as_f(p1 & ~255); g1 = (c1 >> 2) * 16 + g * 4 + (c1 & 3);
            v2 = i_as_f(p2 & ~255); g2 = (c2 >> 2) * 16 + g * 4 + (c2 & 3);
        }
        #pragma unroll
        for (int m = 16; m <= 32; m <<= 1) {
            float ov0 = __shfl_xor(v0, m), ov1 = __shfl_xor(v1, m), ov2 = __shfl_xor(v2, m);
            int   og0 = __shfl_xor(g0, m), og1 = __shfl_xor(g1, m), og2 = __shfl_xor(g2, m);
            insd(ov0, og0, v0, v1, v2, g0, g1, g2);
            insd(ov1, og1, v0, v1, v2, g0, g1, g2);
            insd(ov2, og2, v0, v1, v2, g0, g1, g2);
        }
        if (g == 0) {
            int lv = wave * 32 + b * 16 + lrow;
            scand[lv][0] = g0; scand[lv][1] = g1; scand[lv][2] = g2;
        }
    }
    __syncthreads();

    // ---- fused exact rescore (bit-replicates reference), 2 threads/vector ----
    const int vid = tid & (VPB - 1);
    const int sub = tid >> 7;
    const size_t n = (size_t)blockIdx.x * VPB + vid;
    {
        const float4* z4 = reinterpret_cast<const float4*>(z_e + n * D);
        if (sub == 0) {
            int ci0 = scand[vid][0];
            const float4* cp0 = reinterpret_cast<const float4*>(cb + (size_t)ci0 * D);
            float4 pq = make_float4(0.f, 0.f, 0.f, 0.f);
            float4 s0 = pq;
            #pragma unroll
            for (int i = 0; i < 16; ++i) {
                float4 zz = z4[i];
                pq = f4fma(zz, zz, pq);
                s0 = f4fma(zz, cp0[i], s0);
            }
            sZsq[vid] = f4rsum(pq);
            sS1[vid]  = f4rsum(s0);   // cand0 dot
        } else {
            int ci1 = scand[vid][1];
            int ci2 = scand[vid][2];
            const float4* cp1 = reinterpret_cast<const float4*>(cb + (size_t)ci1 * D);
            const float4* cp2 = reinterpret_cast<const float4*>(cb + (size_t)ci2 * D);
            float4 s1 = make_float4(0.f, 0.f, 0.f, 0.f);
            float4 s2 = s1;
            #pragma unroll
            for (int i = 0; i < 16; ++i) {
                float4 zz = z4[i];
                s1 = f4fma(zz, cp1[i], s1);
                s2 = f4fma(zz, cp2[i], s2);
            }
            sS2[vid] = f4rsum(s1);    // cand1 dot
            sC2[vid] = f4rsum(s2);    // cand2 dot
        }
    }
    __syncthreads();

    float v = 0.f;
    if (sub == 0) {
        int ci0 = scand[vid][0], ci1 = scand[vid][1], ci2 = scand[vid][2];
        float zsq = sZsq[vid];
        float d0 = fmaf(-2.0f, sS1[vid], zsq + esq[ci0]);
        float d1 = fmaf(-2.0f, sS2[vid], zsq + esq[ci1]);
        float d2 = fmaf(-2.0f, sC2[vid], zsq + esq[ci2]);
        float bd = d0; int bi = ci0;
        if (d1 < bd || (d1 == bd && ci1 < bi)) { bd = d1; bi = ci1; }
        if (d2 < bd || (d2 == bd && ci2 < bi)) { bd = d2; bi = ci2; }
        idx_out[n] = (float)bi;
        atomicAdd(&counts[bi], 1);
        scand[vid][0] = bi;            // winner (scand slot reused)
        v = bd;
    }
    #pragma unroll
    for (int off = 32; off > 0; off >>= 1) v += __shfl_down(v, off);
    if ((tid & 63) == 0) sred[tid >> 6] = v;
    __syncthreads();   // winners + sred ready
    if (tid == 0) atomicAdd(sse, (sred[0] + sred[1]) + (sred[2] + sred[3]));

    // ---- coalesced z_q write: 128 vectors * 16 float4 ----
    const float4* cb4 = reinterpret_cast<const float4*>(cb);
    float4* zq4 = reinterpret_cast<float4*>(zq_out) + (size_t)blockIdx.x * (VPB * 16);
    #pragma unroll
    for (int i = 0; i < 8; ++i) {
        int mi  = i * BLK + tid;      // 0..2047
        int vec = mi >> 4;
        int e   = mi & 15;
        zq4[mi] = cb4[(size_t)scand[vec][0] * 16 + e];
    }
}

__global__ void finalize_kernel(const int* __restrict__ counts, const float* __restrict__ sse,
                                float* __restrict__ out_loss, float* __restrict__ out_perp) {
    __shared__ float red[256];
    int tid = threadIdx.x;
    float hsum = 0.f;
    for (int k = tid; k < KCODES; k += 256) {
        float p = (float)counts[k] / (float)N_VEC;
        hsum += p * logf(p + 1e-12f);
    }
    red[tid] = hsum;
    __syncthreads();
    for (int s = 128; s > 0; s >>= 1) {
        if (tid < s) red[tid] += red[tid + s];
        __syncthreads();
    }
    if (tid == 0) {
        out_loss[0] = 1.25f * sse[0] / 8388608.0f;   // (1+BETA) * mean
        out_perp[0] = expf(-red[0]);
    }
}

extern "C" void kernel_launch(void* const* d_in, const int* in_sizes, int n_in,
                              void* d_out, int out_size, void* d_ws, size_t ws_size,
                              hipStream_t stream) {
    const float* z_e = (const float*)d_in[0];
    const float* cb  = (const float*)d_in[1];

    float* out  = (float*)d_out;
    float* zq   = out;
    float* idxo = out + (size_t)N_VEC * D;          // 8388608
    float* loss = idxo + N_VEC;                     // +131072
    float* perp = loss + 1;

    char* ws = (char*)d_ws;
    int*    counts = (int*)ws;
    float*  sse    = (float*)(ws + 4096);
    float*  esq    = (float*)(ws + 5120);
    float4* efrag  = (float4*)(ws + 16384);
    bf16x8* afrag  = (bf16x8*)(ws + 81920);

    hipMemsetAsync(d_ws, 0, 5120, stream);          // zero counts + sse each call
    prep_kernel<<<16, 256, 0, stream>>>(cb, esq, afrag, efrag);
    vq_fused<<<N_VEC / VPB, BLK, 0, stream>>>(z_e, cb, esq, (const float4*)afrag, efrag,
                                              zq, idxo, sse, counts);
    finalize_kernel<<<1, 256, 0, stream>>>(counts, sse, loss, perp);
}

// Round 23
// 104.561 us; speedup vs baseline: 1.1662x; 1.0017x over previous
//
#include <hip/hip_runtime.h>

#define N_VEC   131072
#define D       64
#define KCODES  1024
#define NT      64            // code tiles of 16
#define BLK     256
#define VPB     128           // vectors per block (32 per wave: 2 b-tiles)
#define CH      4             // code tiles staged per LDS chunk
#define NCH     (NT / CH)     // 16 chunks

typedef __attribute__((ext_vector_type(8))) short bf16x8;
typedef __attribute__((ext_vector_type(4))) float f32x4;

// direct global->LDS 16B DMA (no VGPR round trip; LDS dest linear in lane id)
#define GLD16(dst, src) __builtin_amdgcn_global_load_lds(                      \
    (const __attribute__((address_space(1))) void*)(src),                      \
    (__attribute__((address_space(3))) void*)(dst), 16, 0, 0)

// ws layout:
// [0,4096)          int counts[1024]
// [4096,4100)       float sse
// [5120,9216)       float esq[1024]
// [16384,81920)     float4 efrag[64*64]      (einit = -esq/2 in C-row fragment order)
// [81920,344064)    bf16x8 afrag[64*4*64]    (codebook hi/lo MFMA A-fragments)

__device__ __forceinline__ float4 f4fma(float4 a, float4 b, float4 c) {
    return make_float4(fmaf(a.x, b.x, c.x), fmaf(a.y, b.y, c.y),
                       fmaf(a.z, b.z, c.z), fmaf(a.w, b.w, c.w));
}
__device__ __forceinline__ float f4rsum(float4 a) {
    return (a.x + a.y) + (a.z + a.w);
}
__device__ __forceinline__ unsigned short f2bf(float f) {
    union { float f; unsigned u; } x; x.f = f;
    unsigned r = x.u + 0x7FFFu + ((x.u >> 16) & 1u);
    return (unsigned short)(r >> 16);
}
__device__ __forceinline__ float bf2f(unsigned short h) {
    union { unsigned u; float f; } x; x.u = ((unsigned)h) << 16;
    return x.f;
}
__device__ __forceinline__ int   f_as_i(float f) { union { float f; int i; } x; x.f = f; return x.i; }
__device__ __forceinline__ float i_as_f(int i)   { union { int i; float f; } x; x.i = i; return x.f; }

// packed-domain sorted-3 insert: min + med3 + 2 max (validated net, R13)
__device__ __forceinline__ void pins(float pd, float& m1, float& m2, float& m3) {
    float mn = fminf(m2, pd);
    float md = __builtin_amdgcn_fmed3f(m1, pd, m2);
    m1 = fmaxf(m1, pd);
    m2 = md;
    m3 = fmaxf(m3, mn);
}

// esq + codebook MFMA A-fragments (hi/lo bf16 planes) + einit fragment table.
__global__ void prep_kernel(const float* __restrict__ cb, float* __restrict__ esq,
                            bf16x8* __restrict__ afrag, float4* __restrict__ efrag) {
    __shared__ float sesq[64];
    const int tid = threadIdx.x;
    const int c0  = blockIdx.x * 64;
    if (tid < 64) {
        const float4* c4 = reinterpret_cast<const float4*>(cb + (size_t)(c0 + tid) * D);
        float4 p = make_float4(0.f, 0.f, 0.f, 0.f);
        #pragma unroll
        for (int i = 0; i < 16; ++i) { float4 v = c4[i]; p = f4fma(v, v, p); }
        float e = f4rsum(p);
        esq[c0 + tid] = e;
        sesq[tid] = e;
    }
    __syncthreads();
    const int tt = tid >> 6;             // local tile 0..3
    const int L  = tid & 63;
    const int t  = blockIdx.x * 4 + tt;  // global tile
    const int g  = L >> 4;
    const int r  = t * 16 + (L & 15);
    #pragma unroll
    for (int ks = 0; ks < 2; ++ks) {
        const float* src = cb + (size_t)r * D + ks * 32 + g * 8;
        bf16x8 h, l;
        #pragma unroll
        for (int e = 0; e < 8; ++e) {
            float f = src[e];
            unsigned short hb = f2bf(f);
            float lo = f - bf2f(hb);
            h[e] = (short)hb;
            l[e] = (short)f2bf(lo);
        }
        afrag[(t * 4 + ks * 2 + 0) * 64 + L] = h;
        afrag[(t * 4 + ks * 2 + 1) * 64 + L] = l;
    }
    // einit = -esq/2 in C/D fragment layout (lane reg j <-> code row g*4+j)
    float4 ef;
    ef.x = -0.5f * sesq[tt * 16 + g * 4 + 0];
    ef.y = -0.5f * sesq[tt * 16 + g * 4 + 1];
    ef.z = -0.5f * sesq[tt * 16 + g * 4 + 2];
    ef.w = -0.5f * sesq[tt * 16 + g * 4 + 3];
    efrag[t * 64 + L] = ef;
}

// descending (value, idx) lexicographic insert into sorted-3 list
__device__ __forceinline__ void insd(float ov, int og,
                                     float& v0, float& v1, float& v2,
                                     int& g0, int& g1, int& g2) {
    bool b1 = (ov > v0) || (ov == v0 && og < g0);
    bool b2 = (ov > v1) || (ov == v1 && og < g1);
    bool b3 = (ov > v2) || (ov == v2 && og < g2);
    float nv2 = b2 ? v1 : (b3 ? ov : v2);
    int   ng2 = b2 ? g1 : (b3 ? og : g2);
    float nv1 = b1 ? v0 : (b2 ? ov : v1);
    int   ng1 = b1 ? g0 : (b2 ? og : g1);
    v0 = b1 ? ov : v0;
    g0 = b1 ? og : g0;
    v1 = nv1; g1 = ng1; v2 = nv2; g2 = ng2;
}

__launch_bounds__(BLK)
__global__ void vq_fused(const float* __restrict__ z_e, const float* __restrict__ cb,
                         const float* __restrict__ esq,
                         const float4* __restrict__ afrag4, const float4* __restrict__ efrag,
                         float* __restrict__ zq_out, float* __restrict__ idx_out,
                         float* __restrict__ sse, int* __restrict__ counts) {
    __shared__ float4 scb[2][CH * 4 * 64];   // 2 x 16 KB (double-buffered A-frags)
    __shared__ float4 sef[2][CH * 64];       // 2 x 4 KB  (einit frags)
    // epilogue overlays on scb[0] (dead after main loop + barrier); disjoint ranges:
    // scand [0,1536) | sZsq [2048,2560) | sS1 [2560,3072) | sS2 [3072,3584)
    // sC2  [3584,4096) | sred [4096,4112)
    char* ovl = (char*)&scb[0][0];
    int  (*scand)[3] = reinterpret_cast<int(*)[3]>(ovl);
    float* sZsq = reinterpret_cast<float*>(ovl + 2048);
    float* sS1  = reinterpret_cast<float*>(ovl + 2560);
    float* sS2  = reinterpret_cast<float*>(ovl + 3072);
    float* sC2  = reinterpret_cast<float*>(ovl + 3584);
    float* sred = reinterpret_cast<float*>(ovl + 4096);

    const int tid  = threadIdx.x;
    const int wave = tid >> 6;
    const int L    = tid & 63;
    const int lrow = L & 15;
    const int g    = L >> 4;
    const size_t vbase = (size_t)blockIdx.x * VPB + wave * 32;

    // ---- B-fragments: 2 vector-tiles of 16, hi/lo bf16 split, k = g*8+e ----
    bf16x8 zhi[2][2], zlo[2][2];
    #pragma unroll
    for (int b = 0; b < 2; ++b) {
        #pragma unroll
        for (int ks = 0; ks < 2; ++ks) {
            const float* zp = z_e + (vbase + b * 16 + lrow) * D + ks * 32 + g * 8;
            float4 u0 = *reinterpret_cast<const float4*>(zp);
            float4 u1 = *reinterpret_cast<const float4*>(zp + 4);
            float fv[8] = {u0.x, u0.y, u0.z, u0.w, u1.x, u1.y, u1.z, u1.w};
            bf16x8 h, l;
            #pragma unroll
            for (int e = 0; e < 8; ++e) {
                unsigned short hb = f2bf(fv[e]);
                float lo = fv[e] - bf2f(hb);
                h[e] = (short)hb;
                l[e] = (short)f2bf(lo);
            }
            zhi[b][ks] = h; zlo[b][ks] = l;
        }
    }

    // per-j independent packed top-3 streams (8 parallel chains, merged at end)
    float mm1[2][4], mm2[2][4], mm3[2][4];
    #pragma unroll
    for (int b = 0; b < 2; ++b)
        #pragma unroll
        for (int j = 0; j < 4; ++j) { mm1[b][j] = mm2[b][j] = mm3[b][j] = -INFINITY; }

    // prologue: stage chunk 0 into buffer 0
    #pragma unroll
    for (int i = 0; i < 4; ++i) GLD16(&scb[0][i * BLK + tid], afrag4 + i * BLK + tid);
    GLD16(&sef[0][tid], efrag + tid);

    int cur = 0;
    for (int c = 0; c < NCH; ++c) {
        __syncthreads();   // drains vmcnt -> buf[cur] ready; prev compute done
        if (c + 1 < NCH) {
            const float4* gA = afrag4 + (size_t)(c + 1) * (CH * 4 * 64);
            const float4* gE = efrag + (size_t)(c + 1) * (CH * 64);
            #pragma unroll
            for (int i = 0; i < 4; ++i) GLD16(&scb[cur ^ 1][i * BLK + tid], gA + i * BLK + tid);
            GLD16(&sef[cur ^ 1][tid], gE + tid);
        }

        #pragma unroll
        for (int tt = 0; tt < CH; ++tt) {
            const int t = c * CH + tt;
            const bf16x8* fr = reinterpret_cast<const bf16x8*>(&scb[cur][tt * 256]);
            bf16x8 Ah0 = fr[0 * 64 + L];
            bf16x8 Al0 = fr[1 * 64 + L];
            bf16x8 Ah1 = fr[2 * 64 + L];
            bf16x8 Al1 = fr[3 * 64 + L];
            f32x4 einit;
            {
                float4 ef = sef[cur][tt * 64 + L];   // -esq/2
                einit[0] = ef.x; einit[1] = ef.y; einit[2] = ef.z; einit[3] = ef.w;
            }

            #pragma unroll
            for (int b = 0; b < 2; ++b) {
                // single 6-deep chain; C-init = -esq/2 -> acc = dot - esq/2
                f32x4 acc;
                acc = __builtin_amdgcn_mfma_f32_16x16x32_bf16(Ah0, zhi[b][0], einit, 0, 0, 0);
                acc = __builtin_amdgcn_mfma_f32_16x16x32_bf16(Ah0, zlo[b][0], acc, 0, 0, 0);
                acc = __builtin_amdgcn_mfma_f32_16x16x32_bf16(Al0, zhi[b][0], acc, 0, 0, 0);
                acc = __builtin_amdgcn_mfma_f32_16x16x32_bf16(Ah1, zhi[b][1], acc, 0, 0, 0);
                acc = __builtin_amdgcn_mfma_f32_16x16x32_bf16(Ah1, zlo[b][1], acc, 0, 0, 0);
                acc = __builtin_amdgcn_mfma_f32_16x16x32_bf16(Al1, zhi[b][1], acc, 0, 0, 0);

                #pragma unroll
                for (int j = 0; j < 4; ++j) {
                    // pack 8-bit local id (complement: fmax prefers lower code)
                    int komp = 255 - ((t << 2) | j);   // wave-uniform SGPR
                    float pd = i_as_f((f_as_i(acc[j]) & 0xFFFFFF00) | komp);  // v_and_or
                    // independent per-j chain: depth-4 net, 8 parallel streams
                    pins(pd, mm1[b][j], mm2[b][j], mm3[b][j]);
                }
            }
        }
        cur ^= 1;
    }

    __syncthreads();   // all waves done with scb -> overlays safe

    // ---- merge 4 j-streams per b (exact: packed values globally distinct) ----
    // ---- then decode + cross-lane merge with global-idx tie-break ----
    #pragma unroll
    for (int b = 0; b < 2; ++b) {
        float m1 = mm1[b][0], m2 = mm2[b][0], m3 = mm3[b][0];
        #pragma unroll
        for (int j = 1; j < 4; ++j) {
            pins(mm1[b][j], m1, m2, m3);
            pins(mm2[b][j], m1, m2, m3);
            pins(mm3[b][j], m1, m2, m3);
        }
        float v0, v1, v2; int g0, g1, g2;
        {
            int p0 = f_as_i(m1), p1 = f_as_i(m2), p2 = f_as_i(m3);
            int c0 = 255 - (p0 & 255), c1 = 255 - (p1 & 255), c2 = 255 - (p2 & 255);
            v0 = i_as_f(p0 & ~255); g0 = (c0 >> 2) * 16 + g * 4 + (c0 & 3);
            v1 = i_as_f(p1 & ~255); g1 = (c1 >> 2) * 16 + g * 4 + (c1 & 3);
            v2 = i_as_f(p2 & ~255); g2 = (c2 >> 2) * 16 + g * 4 + (c2 & 3);
        }
        #pragma unroll
        for (int m = 16; m <= 32; m <<= 1) {
            float ov0 = __shfl_xor(v0, m), ov1 = __shfl_xor(v1, m), ov2 = __shfl_xor(v2, m);
            int   og0 = __shfl_xor(g0, m), og1 = __shfl_xor(g1, m), og2 = __shfl_xor(g2, m);
            insd(ov0, og0, v0, v1, v2, g0, g1, g2);
            insd(ov1, og1, v0, v1, v2, g0, g1, g2);
            insd(ov2, og2, v0, v1, v2, g0, g1, g2);
        }
        if (g == 0) {
            int lv = wave * 32 + b * 16 + lrow;
            scand[lv][0] = g0; scand[lv][1] = g1; scand[lv][2] = g2;
        }
    }
    __syncthreads();

    // ---- fused exact rescore (bit-replicates reference), 2 threads/vector ----
    const int vid = tid & (VPB - 1);
    const int sub = tid >> 7;
    const size_t n = (size_t)blockIdx.x * VPB + vid;
    {
        const float4* z4 = reinterpret_cast<const float4*>(z_e + n * D);
        if (sub == 0) {
            int ci0 = scand[vid][0];
            const float4* cp0 = reinterpret_cast<const float4*>(cb + (size_t)ci0 * D);
            float4 pq = make_float4(0.f, 0.f, 0.f, 0.f);
            float4 s0 = pq;
            #pragma unroll
            for (int i = 0; i < 16; ++i) {
                float4 zz = z4[i];
                pq = f4fma(zz, zz, pq);
                s0 = f4fma(zz, cp0[i], s0);
            }
            sZsq[vid] = f4rsum(pq);
            sS1[vid]  = f4rsum(s0);   // cand0 dot
        } else {
            int ci1 = scand[vid][1];
            int ci2 = scand[vid][2];
            const float4* cp1 = reinterpret_cast<const float4*>(cb + (size_t)ci1 * D);
            const float4* cp2 = reinterpret_cast<const float4*>(cb + (size_t)ci2 * D);
            float4 s1 = make_float4(0.f, 0.f, 0.f, 0.f);
            float4 s2 = s1;
            #pragma unroll
            for (int i = 0; i < 16; ++i) {
                float4 zz = z4[i];
                s1 = f4fma(zz, cp1[i], s1);
                s2 = f4fma(zz, cp2[i], s2);
            }
            sS2[vid] = f4rsum(s1);    // cand1 dot
            sC2[vid] = f4rsum(s2);    // cand2 dot
        }
    }
    __syncthreads();

    float v = 0.f;
    if (sub == 0) {
        int ci0 = scand[vid][0], ci1 = scand[vid][1], ci2 = scand[vid][2];
        float zsq = sZsq[vid];
        float d0 = fmaf(-2.0f, sS1[vid], zsq + esq[ci0]);
        float d1 = fmaf(-2.0f, sS2[vid], zsq + esq[ci1]);
        float d2 = fmaf(-2.0f, sC2[vid], zsq + esq[ci2]);
        float bd = d0; int bi = ci0;
        if (d1 < bd || (d1 == bd && ci1 < bi)) { bd = d1; bi = ci1; }
        if (d2 < bd || (d2 == bd && ci2 < bi)) { bd = d2; bi = ci2; }
        idx_out[n] = (float)bi;
        atomicAdd(&counts[bi], 1);
        scand[vid][0] = bi;            // winner (scand slot reused)
        v = bd;
    }
    #pragma unroll
    for (int off = 32; off > 0; off >>= 1) v += __shfl_down(v, off);
    if ((tid & 63) == 0) sred[tid >> 6] = v;
    __syncthreads();   // winners + sred ready
    if (tid == 0) atomicAdd(sse, (sred[0] + sred[1]) + (sred[2] + sred[3]));

    // ---- coalesced z_q write: 128 vectors * 16 float4 ----
    const float4* cb4 = reinterpret_cast<const float4*>(cb);
    float4* zq4 = reinterpret_cast<float4*>(zq_out) + (size_t)blockIdx.x * (VPB * 16);
    #pragma unroll
    for (int i = 0; i < 8; ++i) {
        int mi  = i * BLK + tid;      // 0..2047
        int vec = mi >> 4;
        int e   = mi & 15;
        zq4[mi] = cb4[(size_t)scand[vec][0] * 16 + e];
    }
}

__global__ void finalize_kernel(const int* __restrict__ counts, const float* __restrict__ sse,
                                float* __restrict__ out_loss, float* __restrict__ out_perp) {
    __shared__ float red[256];
    int tid = threadIdx.x;
    float hsum = 0.f;
    for (int k = tid; k < KCODES; k += 256) {
        float p = (float)counts[k] / (float)N_VEC;
        hsum += p * logf(p + 1e-12f);
    }
    red[tid] = hsum;
    __syncthreads();
    for (int s = 128; s > 0; s >>= 1) {
        if (tid < s) red[tid] += red[tid + s];
        __syncthreads();
    }
    if (tid == 0) {
        out_loss[0] = 1.25f * sse[0] / 8388608.0f;   // (1+BETA) * mean
        out_perp[0] = expf(-red[0]);
    }
}

extern "C" void kernel_launch(void* const* d_in, const int* in_sizes, int n_in,
                              void* d_out, int out_size, void* d_ws, size_t ws_size,
                              hipStream_t stream) {
    const float* z_e = (const float*)d_in[0];
    const float* cb  = (const float*)d_in[1];

    float* out  = (float*)d_out;
    float* zq   = out;
    float* idxo = out + (size_t)N_VEC * D;          // 8388608
    float* loss = idxo + N_VEC;                     // +131072
    float* perp = loss + 1;

    char* ws = (char*)d_ws;
    int*    counts = (int*)ws;
    float*  sse    = (float*)(ws + 4096);
    float*  esq    = (float*)(ws + 5120);
    float4* efrag  = (float4*)(ws + 16384);
    bf16x8* afrag  = (bf16x8*)(ws + 81920);

    hipMemsetAsync(d_ws, 0, 5120, stream);          // zero counts + sse each call
    prep_kernel<<<16, 256, 0, stream>>>(cb, esq, afrag, efrag);
    vq_fused<<<N_VEC / VPB, BLK, 0, stream>>>(z_e, cb, esq, (const float4*)afrag, efrag,
                                              zq, idxo, sse, counts);
    finalize_kernel<<<1, 256, 0, stream>>>(counts, sse, loss, perp);
}